// Round 11
// baseline (97.445 us; speedup 1.0000x reference)
//
#include <hip/hip_runtime.h>

// Problem constants (from reference)
#define Bv   8
#define Kv   2048
#define Sv   1024
#define Hv   256      // elements per row; 64 lanes x 4 each
#define Wv   24
#define WINv 3
#define RB   8        // rows per issue batch (8 outstanding loads per wave)
#define SPW  8        // spans per wave (persistent-wave amortization)

#define NSPAN (Bv * Kv)

// native vector type for nontemporal builtins (HIP float4 struct is rejected)
typedef float nt4 __attribute__((ext_vector_type(4)));

__device__ __forceinline__ float bf16_to_f32(unsigned short u) {
    union { unsigned int i; float f; } c;
    c.i = ((unsigned int)u) << 16;
    return c.f;
}

__device__ __forceinline__ void nt_store4(float* p, float a, float b, float c, float d) {
    nt4 v = {a, b, c, d};
    __builtin_nontemporal_store(v, (nt4*)p);
}

// Persistent-wave layout: 512 blocks x 4 waves; each wave owns 8 contiguous
// spans of one batch (b = blockIdx&7 XCD swizzle). The sniff + id-load
// dependent chain is paid once per 8 spans; all 8 spans' ids/masks prefetch
// up-front so row loads of span j+1 overlap the reduce of span j.
// Per-wave ballot sniff: no __syncthreads anywhere.
// Dtype sniffing (established R5/R6): token fp32 vs bf16, ids i32 vs i64,
// mask u8/i32/i64/f32 — detected from data patterns each launch.
__global__ __launch_bounds__(256) void span_rep_kernel(
    const void* __restrict__ token_reps,
    const int* __restrict__ span_ids,
    const void* __restrict__ span_masks,
    float* __restrict__ out)
{
    const int tid  = threadIdx.x;
    const int lane = tid & 63;

    // ---- per-wave dtype sniff (ballot results are wave-uniform; no barrier)
    const unsigned short* tu = (const unsigned short*)token_reps;
    int e = (tu[2 * lane] >> 7) & 0xFF;
    unsigned long long votes = __ballot(e >= 96 && e <= 144);
    const int tok32 = (__popcll(votes) >= 56) ? 0 : 1;   // fp32 tokens?

    const unsigned char* mbp = (const unsigned char*)span_masks;
    unsigned char bnz = mbp[lane] | mbp[lane + 64];
    int m4 = lane & 3;
    unsigned long long z1  = __ballot(bnz && m4 == 1);                    // uchar
    unsigned long long z23 = __ballot(bnz && (m4 == 2 || m4 == 3));       // fp32
    unsigned long long z84 = __ballot(bnz && m4 == 0 && (lane & 7) == 4); // int32
    const int maskw = z1 ? 0 : (z23 ? 3 : (z84 ? 1 : 2));

    // ids: int32-interleaved => odd slots are ends (>=1); int64 => hi-words = 0.
    const int odd_or = span_ids[1] | span_ids[3] | span_ids[5] | span_ids[7];
    const int ids64 = (odd_or == 0) ? 1 : 0;

    // ---- span assignment: batch = blockIdx&7, 64 blocks/batch,
    // each block 4 waves x SPW spans = 32 contiguous spans.
    const int b     = blockIdx.x & 7;
    const int kbase = ((blockIdx.x >> 3) << 5) + ((tid >> 6) << 3);  // *32, *8
    const int span0 = b * Kv + kbase;

    // ---- prefetch ids + masks for all SPW spans (independent, L2-hot)
    int st[SPW], en[SPW], mvv[SPW];
    #pragma unroll
    for (int j = 0; j < SPW; ++j) {
        const int span = span0 + j;
        if (!ids64) {
            st[j] = span_ids[2 * span];
            en[j] = span_ids[2 * span + 1];
        } else {
            st[j] = span_ids[4 * span];       // lo word of int64 elem 2*span
            en[j] = span_ids[4 * span + 2];   // lo word of int64 elem 2*span+1
        }
        if (maskw == 0)      mvv[j] = ((const unsigned char*)span_masks)[span];
        else if (maskw == 1) mvv[j] = ((const int*)span_masks)[span];
        else if (maskw == 2) mvv[j] = ((const int*)span_masks)[2 * span];
        else                 mvv[j] = (((const float*)span_masks)[span] != 0.0f);
    }

    const size_t batch_off = (size_t)b * Sv * Hv;

    // ---- process the SPW spans
    for (int j = 0; j < SPW; ++j) {
        const int span = span0 + j;
        float* outp = out + (size_t)span * (3 * Hv) + lane * 4;

        const int start = st[j];
        const int w     = en[j] - start;

        if (mvv[j] == 0 || w < 1 || w > Wv || start < 0 || en[j] > Sv) {
            nt_store4(outp,          0.f, 0.f, 0.f, 0.f);
            nt_store4(outp + Hv,     0.f, 0.f, 0.f, 0.f);
            nt_store4(outp + 2 * Hv, 0.f, 0.f, 0.f, 0.f);
            continue;
        }

        const size_t row0 = batch_off + (size_t)start * Hv;

        float s0 = -INFINITY, s1 = -INFINITY, s2 = -INFINITY, s3 = -INFINITY;
        float e0 = -INFINITY, e1 = -INFINITY, e2 = -INFINITY, e3 = -INFINITY;
        float i0 = -INFINITY, i1 = -INFINITY, i2 = -INFINITY, i3 = -INFINITY;

        const int  scut      = (w < WINv) ? w : WINv;            // [0, scut)
        const int  ecut      = (w - WINv > 0) ? (w - WINv) : 0;  // [ecut, w)
        const bool has_inner = (w > 2 * WINv);                   // [WIN, w-WIN)
        const int  icut      = w - WINv;

        auto reduce = [&](int r, float f0, float f1, float f2, float f3) {
            if (r < scut) {
                s0 = fmaxf(s0, f0); s1 = fmaxf(s1, f1);
                s2 = fmaxf(s2, f2); s3 = fmaxf(s3, f3);
            }
            if (r >= ecut) {
                e0 = fmaxf(e0, f0); e1 = fmaxf(e1, f1);
                e2 = fmaxf(e2, f2); e3 = fmaxf(e3, f3);
            }
            if (has_inner && r >= WINv && r < icut) {
                i0 = fmaxf(i0, f0); i1 = fmaxf(i1, f1);
                i2 = fmaxf(i2, f2); i3 = fmaxf(i3, f3);
            }
        };

        // RB-batched row loads: RB independent loads in flight, then reduce.
        // All guards wave-uniform (w uniform per span).
        if (tok32) {
            const float4* tp = (const float4*)((const float*)token_reps + row0) + lane;
            for (int r0 = 0; r0 < w; r0 += RB) {
                const int n = ((w - r0) < RB) ? (w - r0) : RB;
                float4 buf[RB];
                #pragma unroll
                for (int jj = 0; jj < RB; ++jj)
                    if (jj < n) buf[jj] = tp[(size_t)(r0 + jj) * (Hv / 4)];
                #pragma unroll
                for (int jj = 0; jj < RB; ++jj)
                    if (jj < n)
                        reduce(r0 + jj, buf[jj].x, buf[jj].y, buf[jj].z, buf[jj].w);
            }
        } else {
            const unsigned short* tp = (const unsigned short*)token_reps + row0 + lane * 4;
            for (int r0 = 0; r0 < w; r0 += RB) {
                const int n = ((w - r0) < RB) ? (w - r0) : RB;
                ushort4 buf[RB];
                #pragma unroll
                for (int jj = 0; jj < RB; ++jj)
                    if (jj < n) buf[jj] = *(const ushort4*)(tp + (size_t)(r0 + jj) * Hv);
                #pragma unroll
                for (int jj = 0; jj < RB; ++jj)
                    if (jj < n)
                        reduce(r0 + jj,
                               bf16_to_f32(buf[jj].x), bf16_to_f32(buf[jj].y),
                               bf16_to_f32(buf[jj].z), bf16_to_f32(buf[jj].w));
            }
        }
        if (!has_inner) { i0 = s0; i1 = s1; i2 = s2; i3 = s3; }  // no_inner -> start

        nt_store4(outp,          s0, s1, s2, s3);   // start
        nt_store4(outp + Hv,     i0, i1, i2, i3);   // inner
        nt_store4(outp + 2 * Hv, e0, e1, e2, e3);   // end
    }
}

extern "C" void kernel_launch(void* const* d_in, const int* in_sizes, int n_in,
                              void* d_out, int out_size, void* d_ws, size_t ws_size,
                              hipStream_t stream) {
    // Identify inputs by element count (robust to ordering changes):
    // token_reps = 2,097,152; span_ids = 65,536; span_masks = 16,384.
    const void* token_reps = d_in[0];
    const int*  span_ids   = (const int*)d_in[1];
    const void* span_masks = d_in[2];
    for (int i = 0; i < n_in; ++i) {
        if (in_sizes[i] == Bv * Sv * Hv)      token_reps = d_in[i];
        else if (in_sizes[i] == Bv * Kv * 2)  span_ids   = (const int*)d_in[i];
        else if (in_sizes[i] == Bv * Kv)      span_masks = d_in[i];
    }
    float* out = (float*)d_out;

    // 16384 spans / (4 waves * SPW spans) = 512 blocks
    dim3 grid(NSPAN / (4 * SPW));
    dim3 block(256);
    span_rep_kernel<<<grid, block, 0, stream>>>(token_reps, span_ids, span_masks, out);
}

// Round 12
// 93.024 us; speedup vs baseline: 1.0475x; 1.0475x over previous
//
#include <hip/hip_runtime.h>

// Problem constants (from reference)
#define Bv   8
#define Kv   2048
#define Sv   1024
#define Hv   256      // elements per row; 64 lanes x 4 each
#define Wv   24
#define WINv 3
#define RB   8        // rows per issue batch

#define NSPAN (Bv * Kv)

// native vector type for nontemporal builtins (HIP float4 struct is rejected)
typedef float nt4 __attribute__((ext_vector_type(4)));

__device__ __forceinline__ float bf16_to_f32(unsigned short u) {
    union { unsigned int i; float f; } c;
    c.i = ((unsigned int)u) << 16;
    return c.f;
}

__device__ __forceinline__ void nt_store4(float* p, float a, float b, float c, float d) {
    nt4 v = {a, b, c, d};
    __builtin_nontemporal_store(v, (nt4*)p);
}

__device__ __forceinline__ void cvt4(const float4 v, float* f) {
    f[0] = v.x; f[1] = v.y; f[2] = v.z; f[3] = v.w;
}
__device__ __forceinline__ void cvt4(const ushort4 u, float* f) {
    f[0] = bf16_to_f32(u.x); f[1] = bf16_to_f32(u.y);
    f[2] = bf16_to_f32(u.z); f[3] = bf16_to_f32(u.w);
}

// acc layout: [0..3]=start, [4..7]=inner, [8..11]=end
__device__ __forceinline__ void red(float* acc, int r, int scut, int ecut,
                                    bool hin, int icut, const float* f) {
    if (r < scut) {
        acc[0] = fmaxf(acc[0], f[0]); acc[1] = fmaxf(acc[1], f[1]);
        acc[2] = fmaxf(acc[2], f[2]); acc[3] = fmaxf(acc[3], f[3]);
    }
    if (r >= ecut) {
        acc[8] = fmaxf(acc[8], f[0]); acc[9] = fmaxf(acc[9], f[1]);
        acc[10] = fmaxf(acc[10], f[2]); acc[11] = fmaxf(acc[11], f[3]);
    }
    if (hin && r >= WINv && r < icut) {
        acc[4] = fmaxf(acc[4], f[0]); acc[5] = fmaxf(acc[5], f[1]);
        acc[6] = fmaxf(acc[6], f[2]); acc[7] = fmaxf(acc[7], f[3]);
    }
}

// Process two spans concurrently in one wave: issue A-batch, issue B-batch,
// consume A, consume B -> two spans' load-latency rounds overlap (16 loads
// in flight) without sacrificing wave count (R11 lesson: TLP >> per-wave
// amortization). VT = float4 (fp32 tokens) or ushort4 (bf16), STRIDEB = row
// byte stride. w==0 encodes invalid span (store zeros).
template<typename VT, int STRIDEB>
__device__ __forceinline__ void pair_body(
    const char* pA, const char* pB, int wA, int wB,
    float* outA, float* outB)
{
    float accA[12], accB[12];
    #pragma unroll
    for (int q = 0; q < 12; ++q) { accA[q] = -INFINITY; accB[q] = -INFINITY; }

    const int  scutA = (wA < WINv) ? wA : WINv;
    const int  ecutA = (wA - WINv > 0) ? (wA - WINv) : 0;
    const bool hinA  = wA > 2 * WINv;
    const int  icutA = wA - WINv;
    const int  scutB = (wB < WINv) ? wB : WINv;
    const int  ecutB = (wB - WINv > 0) ? (wB - WINv) : 0;
    const bool hinB  = wB > 2 * WINv;
    const int  icutB = wB - WINv;

    for (int r0 = 0; r0 < Wv; r0 += RB) {
        if (r0 >= wA && r0 >= wB) break;
        VT bA[RB], bB[RB];
        // issue A then B: both batches in flight before first consume
        #pragma unroll
        for (int j = 0; j < RB; ++j)
            if (r0 + j < wA) bA[j] = *(const VT*)(pA + (size_t)(r0 + j) * STRIDEB);
        #pragma unroll
        for (int j = 0; j < RB; ++j)
            if (r0 + j < wB) bB[j] = *(const VT*)(pB + (size_t)(r0 + j) * STRIDEB);
        #pragma unroll
        for (int j = 0; j < RB; ++j)
            if (r0 + j < wA) {
                float f[4]; cvt4(bA[j], f);
                red(accA, r0 + j, scutA, ecutA, hinA, icutA, f);
            }
        #pragma unroll
        for (int j = 0; j < RB; ++j)
            if (r0 + j < wB) {
                float f[4]; cvt4(bB[j], f);
                red(accB, r0 + j, scutB, ecutB, hinB, icutB, f);
            }
    }

    if (wA == 0) {
        nt_store4(outA, 0.f, 0.f, 0.f, 0.f);
        nt_store4(outA + Hv, 0.f, 0.f, 0.f, 0.f);
        nt_store4(outA + 2 * Hv, 0.f, 0.f, 0.f, 0.f);
    } else {
        if (!hinA) { accA[4] = accA[0]; accA[5] = accA[1];
                     accA[6] = accA[2]; accA[7] = accA[3]; }
        nt_store4(outA,          accA[0], accA[1], accA[2], accA[3]);
        nt_store4(outA + Hv,     accA[4], accA[5], accA[6], accA[7]);
        nt_store4(outA + 2 * Hv, accA[8], accA[9], accA[10], accA[11]);
    }
    if (wB == 0) {
        nt_store4(outB, 0.f, 0.f, 0.f, 0.f);
        nt_store4(outB + Hv, 0.f, 0.f, 0.f, 0.f);
        nt_store4(outB + 2 * Hv, 0.f, 0.f, 0.f, 0.f);
    } else {
        if (!hinB) { accB[4] = accB[0]; accB[5] = accB[1];
                     accB[6] = accB[2]; accB[7] = accB[3]; }
        nt_store4(outB,          accB[0], accB[1], accB[2], accB[3]);
        nt_store4(outB + Hv,     accB[4], accB[5], accB[6], accB[7]);
        nt_store4(outB + 2 * Hv, accB[8], accB[9], accB[10], accB[11]);
    }
}

// 2048 blocks x 4 waves x 2 spans = 16384 spans. b = blockIdx&7 XCD swizzle.
// Per-wave ballot dtype sniff (no __syncthreads). Dtype sniffing established
// R5/R6: token fp32 vs bf16, ids i32 vs i64, mask u8/f32/i32/i64.
__global__ __launch_bounds__(256) void span_rep_kernel(
    const void* __restrict__ token_reps,
    const int* __restrict__ span_ids,
    const void* __restrict__ span_masks,
    float* __restrict__ out)
{
    const int tid  = threadIdx.x;
    const int lane = tid & 63;

    // ---- per-wave dtype sniff (ballot results are wave-uniform)
    const unsigned short* tu = (const unsigned short*)token_reps;
    int e = (tu[2 * lane] >> 7) & 0xFF;
    unsigned long long votes = __ballot(e >= 96 && e <= 144);
    const int tok32 = (__popcll(votes) >= 56) ? 0 : 1;   // fp32 tokens?

    const unsigned char* mbp = (const unsigned char*)span_masks;
    unsigned char bnz = mbp[lane] | mbp[lane + 64];
    int m4 = lane & 3;
    unsigned long long z1  = __ballot(bnz && m4 == 1);                    // uchar
    unsigned long long z23 = __ballot(bnz && (m4 == 2 || m4 == 3));       // fp32
    unsigned long long z84 = __ballot(bnz && m4 == 0 && (lane & 7) == 4); // int32
    const int maskw = z1 ? 0 : (z23 ? 3 : (z84 ? 1 : 2));

    const int odd_or = span_ids[1] | span_ids[3] | span_ids[5] | span_ids[7];
    const int ids64 = (odd_or == 0) ? 1 : 0;

    // ---- span pair assignment
    const int b  = blockIdx.x & 7;
    const int k0 = ((blockIdx.x >> 3) << 3) + ((tid >> 6) << 1);  // blk*8 + wave*2
    const int sA = b * Kv + k0;
    const int sB = sA + 1;

    // ---- decode ids + masks for both spans (independent loads, L2-hot)
    int stA, enA, stB, enB, mvA, mvB;
    if (!ids64) {
        stA = span_ids[2 * sA];     enA = span_ids[2 * sA + 1];
        stB = span_ids[2 * sB];     enB = span_ids[2 * sB + 1];
    } else {
        stA = span_ids[4 * sA];     enA = span_ids[4 * sA + 2];
        stB = span_ids[4 * sB];     enB = span_ids[4 * sB + 2];
    }
    if (maskw == 0)      { mvA = ((const unsigned char*)span_masks)[sA];
                           mvB = ((const unsigned char*)span_masks)[sB]; }
    else if (maskw == 1) { mvA = ((const int*)span_masks)[sA];
                           mvB = ((const int*)span_masks)[sB]; }
    else if (maskw == 2) { mvA = ((const int*)span_masks)[2 * sA];
                           mvB = ((const int*)span_masks)[2 * sB]; }
    else                 { mvA = (((const float*)span_masks)[sA] != 0.0f);
                           mvB = (((const float*)span_masks)[sB] != 0.0f); }

    int wA = enA - stA;
    int wB = enB - stB;
    // w==0 encodes invalid (store zeros); guard insane decodes too
    if (mvA == 0 || wA < 1 || wA > Wv || stA < 0 || enA > Sv) wA = 0;
    if (mvB == 0 || wB < 1 || wB > Wv || stB < 0 || enB > Sv) wB = 0;

    float* outA = out + (size_t)sA * (3 * Hv) + lane * 4;
    float* outB = out + (size_t)sB * (3 * Hv) + lane * 4;

    const size_t batch_off = (size_t)b * Sv * Hv;

    if (tok32) {
        const char* base = (const char*)token_reps;
        const char* pA = base + (batch_off + (size_t)stA * Hv + lane * 4) * 4;
        const char* pB = base + (batch_off + (size_t)stB * Hv + lane * 4) * 4;
        pair_body<float4, Hv * 4>(pA, pB, wA, wB, outA, outB);
    } else {
        const char* base = (const char*)token_reps;
        const char* pA = base + (batch_off + (size_t)stA * Hv + lane * 4) * 2;
        const char* pB = base + (batch_off + (size_t)stB * Hv + lane * 4) * 2;
        pair_body<ushort4, Hv * 2>(pA, pB, wA, wB, outA, outB);
    }
}

extern "C" void kernel_launch(void* const* d_in, const int* in_sizes, int n_in,
                              void* d_out, int out_size, void* d_ws, size_t ws_size,
                              hipStream_t stream) {
    // Identify inputs by element count (robust to ordering changes):
    // token_reps = 2,097,152; span_ids = 65,536; span_masks = 16,384.
    const void* token_reps = d_in[0];
    const int*  span_ids   = (const int*)d_in[1];
    const void* span_masks = d_in[2];
    for (int i = 0; i < n_in; ++i) {
        if (in_sizes[i] == Bv * Sv * Hv)      token_reps = d_in[i];
        else if (in_sizes[i] == Bv * Kv * 2)  span_ids   = (const int*)d_in[i];
        else if (in_sizes[i] == Bv * Kv)      span_masks = d_in[i];
    }
    float* out = (float*)d_out;

    // 16384 spans / (4 waves * 2 spans) = 2048 blocks
    dim3 grid(NSPAN / 8);
    dim3 block(256);
    span_rep_kernel<<<grid, block, 0, stream>>>(token_reps, span_ids, span_masks, out);
}

// Round 13
// 88.873 us; speedup vs baseline: 1.0965x; 1.0467x over previous
//
#include <hip/hip_runtime.h>

// Problem constants (from reference)
#define Bv   8
#define Kv   2048
#define Sv   1024
#define Hv   256      // elements per row; 64 lanes x 4 each
#define Wv   24
#define WINv 3
#define RB   12       // rows per batch; clamped full-depth => max 2 rounds

#define NSPAN (Bv * Kv)

__device__ __forceinline__ float bf16_to_f32(unsigned short u) {
    union { unsigned int i; float f; } c;
    c.i = ((unsigned int)u) << 16;
    return c.f;
}

// Best-known structure (R8): 4096 blocks x 4 waves, one span per wave,
// XCD swizzle b=blockIdx&7, plain coalesced stores.
// Changes vs R8: per-wave ballot sniff (no __syncthreads), speculative
// dual-width id loads, and clamped full-depth RB=12 batches (row index
// min(r,w-1)): every batch issues 12 independent loads (dups = L1 hits),
// so any span needs at most 2 serialized latency rounds (avg 1.5 vs 1.96).
// Dtype sniffing established R5/R6: token fp32 vs bf16, ids i32 vs i64,
// mask u8/f32/i32/i64 — detected from data patterns each launch.
__global__ __launch_bounds__(256) void span_rep_kernel(
    const void* __restrict__ token_reps,
    const int* __restrict__ span_ids,
    const void* __restrict__ span_masks,
    float* __restrict__ out)
{
    const int tid  = threadIdx.x;
    const int lane = tid & 63;

    // ---- per-wave dtype sniff (ballot results are wave-uniform; no barrier)
    const unsigned short* tu = (const unsigned short*)token_reps;
    int e = (tu[2 * lane] >> 7) & 0xFF;
    unsigned long long votes = __ballot(e >= 96 && e <= 144);
    const int tok32 = (__popcll(votes) >= 56) ? 0 : 1;   // fp32 tokens?

    const unsigned char* mbp = (const unsigned char*)span_masks;
    unsigned char bnz = mbp[lane] | mbp[lane + 64];
    int m4 = lane & 3;
    unsigned long long z1  = __ballot(bnz && m4 == 1);                    // uchar
    unsigned long long z23 = __ballot(bnz && (m4 == 2 || m4 == 3));       // fp32
    unsigned long long z84 = __ballot(bnz && m4 == 0 && (lane & 7) == 4); // int32
    const int maskw = z1 ? 0 : (z23 ? 3 : (z84 ? 1 : 2));

    const int odd_or = span_ids[1] | span_ids[3] | span_ids[5] | span_ids[7];
    const int ids64 = (odd_or == 0) ? 1 : 0;

    // ---- span assignment (R8 mapping): b = blockIdx&7, k = blk>>3 * 4 + wave
    const int b    = blockIdx.x & 7;
    const int k    = ((blockIdx.x >> 3) << 2) + (tid >> 6);
    const int span = b * Kv + k;

    float* outp = out + (size_t)span * (3 * Hv) + lane * 4;

    // ---- speculative dual-width id load, then select (no branch dependency)
    int st32 = span_ids[2 * span];
    int en32 = span_ids[2 * span + 1];
    int st64 = span_ids[4 * span];
    int en64 = span_ids[4 * span + 2];
    const int start = ids64 ? st64 : st32;
    const int end   = ids64 ? en64 : en32;

    int mv;
    if (maskw == 0)      mv = ((const unsigned char*)span_masks)[span];
    else if (maskw == 1) mv = ((const int*)span_masks)[span];
    else if (maskw == 2) mv = ((const int*)span_masks)[2 * span];
    else                 mv = (((const float*)span_masks)[span] != 0.0f);

    const int w = end - start;

    if (mv == 0 || w < 1 || w > Wv || start < 0 || end > Sv) {
        float4 z = make_float4(0.f, 0.f, 0.f, 0.f);
        *(float4*)(outp)          = z;   // start section
        *(float4*)(outp + Hv)     = z;   // inner section
        *(float4*)(outp + 2 * Hv) = z;   // end section
        return;
    }

    const size_t row0 = ((size_t)b * Sv + start) * Hv;

    float s0 = -INFINITY, s1 = -INFINITY, s2 = -INFINITY, s3 = -INFINITY;
    float e0 = -INFINITY, e1 = -INFINITY, e2 = -INFINITY, e3 = -INFINITY;
    float i0 = -INFINITY, i1 = -INFINITY, i2 = -INFINITY, i3 = -INFINITY;

    const int  scut      = (w < WINv) ? w : WINv;            // start rows [0, scut)
    const int  ecut      = (w - WINv > 0) ? (w - WINv) : 0;  // end rows [ecut, w)
    const bool has_inner = (w > 2 * WINv);                   // inner rows [WIN, w-WIN)
    const int  icut      = w - WINv;
    const int  wm1       = w - 1;

    auto reduce = [&](int r, float f0, float f1, float f2, float f3) {
        if (r < scut) {
            s0 = fmaxf(s0, f0); s1 = fmaxf(s1, f1);
            s2 = fmaxf(s2, f2); s3 = fmaxf(s3, f3);
        }
        if (r >= ecut) {
            e0 = fmaxf(e0, f0); e1 = fmaxf(e1, f1);
            e2 = fmaxf(e2, f2); e3 = fmaxf(e3, f3);
        }
        if (has_inner && r >= WINv && r < icut) {
            i0 = fmaxf(i0, f0); i1 = fmaxf(i1, f1);
            i2 = fmaxf(i2, f2); i3 = fmaxf(i3, f3);
        }
    };

    // Clamped full-depth batches: all RB loads issue every round (clamped
    // rows duplicate row w-1 -> L1 hits); reduce predicated on real rows.
    // Max 2 rounds (RB=12, Wv=24); w<=12 (50% of spans) = single round.
    if (tok32) {
        const float4* tp = (const float4*)((const float*)token_reps + row0) + lane;
        for (int r0 = 0; r0 < w; r0 += RB) {
            float4 buf[RB];
            #pragma unroll
            for (int j = 0; j < RB; ++j) {
                int rr = r0 + j; rr = (rr < wm1) ? rr : wm1;   // clamp
                buf[j] = tp[(size_t)rr * (Hv / 4)];
            }
            #pragma unroll
            for (int j = 0; j < RB; ++j)
                if (r0 + j < w)
                    reduce(r0 + j, buf[j].x, buf[j].y, buf[j].z, buf[j].w);
        }
    } else {
        const unsigned short* tp = (const unsigned short*)token_reps + row0 + lane * 4;
        for (int r0 = 0; r0 < w; r0 += RB) {
            ushort4 buf[RB];
            #pragma unroll
            for (int j = 0; j < RB; ++j) {
                int rr = r0 + j; rr = (rr < wm1) ? rr : wm1;   // clamp
                buf[j] = *(const ushort4*)(tp + (size_t)rr * Hv);
            }
            #pragma unroll
            for (int j = 0; j < RB; ++j)
                if (r0 + j < w)
                    reduce(r0 + j,
                           bf16_to_f32(buf[j].x), bf16_to_f32(buf[j].y),
                           bf16_to_f32(buf[j].z), bf16_to_f32(buf[j].w));
        }
    }
    if (!has_inner) { i0 = s0; i1 = s1; i2 = s2; i3 = s3; }  // no_inner -> start

    *(float4*)(outp)          = make_float4(s0, s1, s2, s3);   // start
    *(float4*)(outp + Hv)     = make_float4(i0, i1, i2, i3);   // inner
    *(float4*)(outp + 2 * Hv) = make_float4(e0, e1, e2, e3);   // end
}

extern "C" void kernel_launch(void* const* d_in, const int* in_sizes, int n_in,
                              void* d_out, int out_size, void* d_ws, size_t ws_size,
                              hipStream_t stream) {
    // Identify inputs by element count (robust to ordering changes):
    // token_reps = 2,097,152; span_ids = 65,536; span_masks = 16,384.
    const void* token_reps = d_in[0];
    const int*  span_ids   = (const int*)d_in[1];
    const void* span_masks = d_in[2];
    for (int i = 0; i < n_in; ++i) {
        if (in_sizes[i] == Bv * Sv * Hv)      token_reps = d_in[i];
        else if (in_sizes[i] == Bv * Kv * 2)  span_ids   = (const int*)d_in[i];
        else if (in_sizes[i] == Bv * Kv)      span_masks = d_in[i];
    }
    float* out = (float*)d_out;

    // 16384 spans, 4 spans (waves) per 256-thread block = 4096 blocks
    dim3 grid(NSPAN / 4);
    dim3 block(256);
    span_rep_kernel<<<grid, block, 0, stream>>>(token_reps, span_ids, span_masks, out);
}